// Round 9
// baseline (245.712 us; speedup 1.0000x reference)
//
#include <hip/hip_runtime.h>
#include <hip/hip_bf16.h>

// Pipeline (N=50000, E=1.6M, D=16, NK=2):
//   bhist: LDS-private bucket histogram (bucket = dst>>9)
//   bscan: column-sum + scan buckets -> bbase/bcur(padded)/off[N]=E sentinel
//   partA: bucket-partition edges into staging (LDS-staged, coalesced writes)
//   partB: per-bucket node sort -> srcS/kS dst-sorted + off (L2-local writes)
//   conv1+mlp1: half-wave/node, 16-lane group per edge, dual k-acc
//   conv2:      wave per node, 8-lane group per edge, float4 row gather
//   mlp2:       512-thread reg-tiled GEMM, swizzled LDS (bank-conflict-free)
//
// NOTE (round-7 post-mortem): NEVER use atomicAdd on __shared__ float in hot
// loops on gfx950 — it serializes catastrophically (678us vs 59us gather).
// NOTE (round-8 post-mortem): k-major LDS tiles with 16-float rows have
// store bank = f(row mod 8) only -> 16-way conflicts; swizzle col by
// ((row>>3)<<2) & 63 to spread banks while keeping reads broadcast-free.

#define EPSV 1e-12f
#define CHUNK 2048      // edges per partA block
#define NBMAX 128       // bucket slots (nbuck = ceil(N/512) = 98 <= 128)
#define BNODES 512      // nodes per partition bucket (dst >> 9)
#define BCPAD 16        // bcur padding stride (ints) -> 1 cache line per bucket

// ---- detect whether edge_index buffer is int64 (odd int32 words all zero) ----
__global__ void detect_i64_kernel(const int* ei, int* flag) {
    int lane = threadIdx.x;
    int nonzero = 0;
    for (int i = lane; i < 1024; i += 64) {
        if (ei[2 * i + 1] != 0) nonzero = 1;
    }
    unsigned long long b = __ballot(nonzero);
    if (lane == 0) *flag = (b == 0ull) ? 1 : 0;   // 1 => int64 layout
}

__device__ __forceinline__ void load_edge(const int* ei, int e, int E, int flag,
                                          int& src, int& dst) {
    if (flag) {            // int64 storage: low words at even int32 indices
        src = ei[2 * e];
        dst = ei[2 * E + 2 * e];
    } else {               // int32 storage
        src = ei[e];
        dst = ei[E + e];
    }
}

// ---- bucket histogram: LDS-privatized, one cntmat row per block ----
__global__ __launch_bounds__(256) void bhist_kernel(
        const int* __restrict__ ei, const int* __restrict__ flagp,
        int* __restrict__ cntmat, int E) {
    __shared__ int l[NBMAX];
    if (threadIdx.x < NBMAX) l[threadIdx.x] = 0;
    __syncthreads();
    int flag = *flagp;
    int stride = gridDim.x * 256;
    for (int e = blockIdx.x * 256 + threadIdx.x; e < E; e += stride) {
        int dst = flag ? ei[2 * E + 2 * e] : ei[E + e];
        atomicAdd(&l[dst >> 9], 1);
    }
    __syncthreads();
    if (threadIdx.x < NBMAX) cntmat[blockIdx.x * NBMAX + threadIdx.x] = l[threadIdx.x];
}

// ---- column-sum cntmat + exclusive scan of bucket counts ----
__global__ void bscan_kernel(const int* __restrict__ cntmat,
                             int* __restrict__ bbase, int* __restrict__ bcur,
                             int* __restrict__ off,
                             int nbuck, int E, int nrows, int N) {
    __shared__ int s[NBMAX];
    int t = threadIdx.x;            // blockDim = NBMAX
    int c = 0;
    for (int i = 0; i < nrows; ++i) c += cntmat[i * NBMAX + t];
    s[t] = c;
    __syncthreads();
    for (int d = 1; d < NBMAX; d <<= 1) {
        int v = (t >= d) ? s[t - d] : 0;
        __syncthreads();
        s[t] += v;
        __syncthreads();
    }
    int excl = s[t] - c;
    if (t < nbuck) { bbase[t] = excl; bcur[t * BCPAD] = excl; }
    if (t == 0) { bbase[nbuck] = E; off[N] = E; }
}

// ---- partA: bucket-partition edges by dst>>9, LDS-staged ----
__global__ __launch_bounds__(256) void partA_kernel(
        const float* __restrict__ K, const int* __restrict__ ei,
        const int* __restrict__ flagp, int* __restrict__ bcur,
        int4* __restrict__ staging, int E) {
    __shared__ int cnt[NBMAX];
    __shared__ int bexc[NBMAX];
    __shared__ int gbase[NBMAX];
    __shared__ int scanbuf[NBMAX];
    __shared__ int4 stage[CHUNK];     // 32 KB

    int flag = *flagp;
    int e0 = blockIdx.x * CHUNK;
    int tot = min(CHUNK, E - e0);

    for (int b = threadIdx.x; b < NBMAX; b += 256) cnt[b] = 0;
    __syncthreads();

    int  myslot[CHUNK / 256];
    int  mybk[CHUNK / 256];
    int4 myrec[CHUNK / 256];
#pragma unroll
    for (int it = 0; it < CHUNK / 256; ++it) {
        int e = e0 + it * 256 + threadIdx.x;
        mybk[it] = -1;
        if (e < E) {
            int src, dst;
            load_edge(ei, e, E, flag, src, dst);
            int bk = dst >> 9;
            mybk[it] = bk;
            myrec[it] = make_int4(src, __float_as_int(K[e]),
                                  __float_as_int(K[E + e]), dst);
            myslot[it] = atomicAdd(&cnt[bk], 1);
        }
    }
    __syncthreads();

    if (threadIdx.x < NBMAX) scanbuf[threadIdx.x] = cnt[threadIdx.x];
    __syncthreads();
    for (int d = 1; d < NBMAX; d <<= 1) {
        int v = 0;
        if (threadIdx.x < NBMAX && threadIdx.x >= d) v = scanbuf[threadIdx.x - d];
        __syncthreads();
        if (threadIdx.x < NBMAX) scanbuf[threadIdx.x] += v;
        __syncthreads();
    }
    if (threadIdx.x < NBMAX) {
        int c = cnt[threadIdx.x];
        bexc[threadIdx.x] = scanbuf[threadIdx.x] - c;
        gbase[threadIdx.x] = c ? atomicAdd(&bcur[threadIdx.x * BCPAD], c) : 0;
    }
    __syncthreads();

#pragma unroll
    for (int it = 0; it < CHUNK / 256; ++it) {
        if (mybk[it] >= 0) stage[bexc[mybk[it]] + myslot[it]] = myrec[it];
    }
    __syncthreads();

    for (int i = threadIdx.x; i < tot; i += 256) {
        int4 r = stage[i];
        int bk = r.w >> 9;
        staging[gbase[bk] + (i - bexc[bk])] = r;
    }
}

// ---- partB: per-bucket node sort; emits dst-sorted srcS/kS + off ----
__global__ __launch_bounds__(1024) void partB_kernel(
        const int4* __restrict__ staging, const int* __restrict__ bbase,
        int* __restrict__ off, int* __restrict__ srcS,
        float2* __restrict__ kS, int N) {
    __shared__ int lcnt[BNODES];
    __shared__ int lscan[BNODES];

    int b = blockIdx.x;
    int nodeBase = b << 9;
    int s0 = bbase[b];
    int s1 = bbase[b + 1];
    int t = threadIdx.x;

    if (t < BNODES) lcnt[t] = 0;
    __syncthreads();

    for (int i = s0 + t; i < s1; i += 1024)
        atomicAdd(&lcnt[staging[i].w - nodeBase], 1);
    __syncthreads();

    if (t < BNODES) lscan[t] = lcnt[t];
    __syncthreads();
    for (int d = 1; d < BNODES; d <<= 1) {
        int v = 0;
        if (t < BNODES && t >= d) v = lscan[t - d];
        __syncthreads();
        if (t < BNODES) lscan[t] += v;
        __syncthreads();
    }
    if (t < BNODES) {
        int node = nodeBase + t;
        if (node < N) {
            int c = lcnt[t];
            int o = s0 + lscan[t] - c;   // exclusive offset, absolute
            off[node] = o;
            lcnt[t] = o;                 // becomes the cursor
        }
    }
    __syncthreads();

    for (int i = s0 + t; i < s1; i += 1024) {
        int4 r = staging[i];
        int pos = atomicAdd(&lcnt[r.w - nodeBase], 1);
        srcS[pos] = r.x;
        kS[pos] = make_float2(__int_as_float(r.y), __int_as_float(r.z));
    }
}

// ---- conv1 + MLP1: half-wave per node; 16-lane group per edge ----
__global__ __launch_bounds__(256) void conv1_mlp1_kernel(
        const float* __restrict__ x, const int* __restrict__ srcS,
        const float2* __restrict__ kS, const int* __restrict__ off,
        const float* __restrict__ W1, const float* __restrict__ b1,
        float* __restrict__ h1, int N) {
    __shared__ float w[1024];
    __shared__ float bsh[32];
    for (int i = threadIdx.x; i < 1024; i += 256) w[i] = W1[i];
    if (threadIdx.x < 32) bsh[threadIdx.x] = b1[threadIdx.x];
    __syncthreads();

    int hw = threadIdx.x >> 5;        // half-wave 0..7 -> node
    int lane = threadIdx.x & 31;
    int node = blockIdx.x * 8 + hw;
    if (node >= N) return;

    int ch = lane & 15;
    int grp = lane >> 4;              // 0/1: edge parity
    int start = off[node];
    int deg = off[node + 1] - start;

    float a0 = 0.f, a1 = 0.f;
    int j = grp;
    for (; j + 6 < deg; j += 8) {     // edges j, j+2, j+4, j+6
        int p = start + j;
        int s0 = srcS[p], s1 = srcS[p + 2], s2 = srcS[p + 4], s3 = srcS[p + 6];
        float2 k0 = kS[p], k1 = kS[p + 2], k2 = kS[p + 4], k3 = kS[p + 6];
        float v0 = x[s0 * 16 + ch];
        float v1 = x[s1 * 16 + ch];
        float v2 = x[s2 * 16 + ch];
        float v3 = x[s3 * 16 + ch];
        a0 += k0.x * v0; a1 += k0.y * v0;
        a0 += k1.x * v1; a1 += k1.y * v1;
        a0 += k2.x * v2; a1 += k2.y * v2;
        a0 += k3.x * v3; a1 += k3.y * v3;
    }
    for (; j < deg; j += 2) {
        int p = start + j;
        int s = srcS[p];
        float2 kk = kS[p];
        float v = x[s * 16 + ch];
        a0 += kk.x * v; a1 += kk.y * v;
    }
    a0 += __shfl_xor(a0, 16, 32);
    a1 += __shfl_xor(a1, 16, 32);
    float acc = grp ? a1 : a0;

    float o = bsh[lane];
#pragma unroll
    for (int q = 0; q < 32; q++) o += __shfl(acc, q, 32) * w[q * 32 + lane];
    o = fmaxf(o, 0.f);
    float ss = o * o;
#pragma unroll
    for (int m = 16; m >= 1; m >>= 1) ss += __shfl_xor(ss, m, 32);
    h1[node * 32 + lane] = o / fmaxf(sqrtf(ss), EPSV);
}

// ---- conv2: wave per node; 8-lane group per edge; float4 row gather ----
__global__ __launch_bounds__(256) void conv2_gather_kernel(
        const float* __restrict__ h1, const int* __restrict__ srcS,
        const float2* __restrict__ kS, const int* __restrict__ off,
        float* __restrict__ h2, int N) {
    int wid = threadIdx.x >> 6;
    int lane = threadIdx.x & 63;
    int node = blockIdx.x * 4 + wid;
    if (node >= N) return;

    int grp = lane >> 3;              // 0..7: edge index mod 8
    int cq = lane & 7;                // channel quad: ch = cq*4..cq*4+3
    int start = off[node];
    int deg = off[node + 1] - start;

    float a00 = 0.f, a01 = 0.f, a02 = 0.f, a03 = 0.f;   // k0 * row[cq*4..]
    float a10 = 0.f, a11 = 0.f, a12 = 0.f, a13 = 0.f;   // k1 * row[cq*4..]
    int j = grp;
    for (; j + 8 < deg; j += 16) {    // edges j, j+8
        int p0 = start + j, p1 = start + j + 8;
        int s0 = srcS[p0], s1 = srcS[p1];
        float2 k0 = kS[p0], k1 = kS[p1];
        float4 v0 = *(const float4*)&h1[s0 * 32 + cq * 4];
        float4 v1 = *(const float4*)&h1[s1 * 32 + cq * 4];
        a00 += k0.x * v0.x; a01 += k0.x * v0.y; a02 += k0.x * v0.z; a03 += k0.x * v0.w;
        a10 += k0.y * v0.x; a11 += k0.y * v0.y; a12 += k0.y * v0.z; a13 += k0.y * v0.w;
        a00 += k1.x * v1.x; a01 += k1.x * v1.y; a02 += k1.x * v1.z; a03 += k1.x * v1.w;
        a10 += k1.y * v1.x; a11 += k1.y * v1.y; a12 += k1.y * v1.z; a13 += k1.y * v1.w;
    }
    for (; j < deg; j += 8) {
        int p = start + j;
        int s = srcS[p];
        float2 kk = kS[p];
        float4 v = *(const float4*)&h1[s * 32 + cq * 4];
        a00 += kk.x * v.x; a01 += kk.x * v.y; a02 += kk.x * v.z; a03 += kk.x * v.w;
        a10 += kk.y * v.x; a11 += kk.y * v.y; a12 += kk.y * v.z; a13 += kk.y * v.w;
    }

#pragma unroll
    for (int m = 8; m < 64; m <<= 1) {
        a00 += __shfl_xor(a00, m, 64); a01 += __shfl_xor(a01, m, 64);
        a02 += __shfl_xor(a02, m, 64); a03 += __shfl_xor(a03, m, 64);
        a10 += __shfl_xor(a10, m, 64); a11 += __shfl_xor(a11, m, 64);
        a12 += __shfl_xor(a12, m, 64); a13 += __shfl_xor(a13, m, 64);
    }
    if (grp == 0) {
        float4 o = make_float4(a00, a01, a02, a03);
        *(float4*)&h2[(size_t)node * 64 + cq * 4] = o;
    } else if (grp == 1) {
        float4 o = make_float4(a10, a11, a12, a13);
        *(float4*)&h2[(size_t)node * 64 + 32 + cq * 4] = o;
    }
}

// ---- MLP2: 512 threads, 64 nodes/block, swizzled k-major LDS tiles ----
// tile element n of row c lives at col ((n + ((c>>3)<<2)) & 63)
#define SWZ(n, c) (((n) + (((c) >> 3) << 2)) & 63)
__global__ __launch_bounds__(512) void mlp2_kernel(
        const float* __restrict__ h2,
        const float* __restrict__ W2a,
        const float* __restrict__ b2a,
        const float* __restrict__ W2b,
        const float* __restrict__ b2b,
        float* __restrict__ out, int N) {
    __shared__ float xs[64 * 68];    // xs[c][n'] c in [0,64)
    __shared__ float hs[128 * 68];   // hs[c][n'] c in [0,128)

    int tid = threadIdx.x;
    int n0 = blockIdx.x * 64;

    // load + transpose-swizzle X = h2[n0..n0+63][0..63]
#pragma unroll
    for (int it = 0; it < 2; ++it) {
        int idx = tid + it * 512;        // 0..1023
        int n = idx >> 4;
        int c4 = (idx & 15) * 4;
        float4 v = make_float4(0.f, 0.f, 0.f, 0.f);
        if (n0 + n < N) v = *(const float4*)&h2[(size_t)(n0 + n) * 64 + c4];
        float vv[4] = {v.x, v.y, v.z, v.w};
#pragma unroll
        for (int u = 0; u < 4; ++u) {
            int c = c4 + u;
            xs[c * 68 + SWZ(n, c)] = vv[u];
        }
    }
    __syncthreads();

    int rg = tid >> 4;     // 0..31: rows rg*2, rg*2+1
    int cg = tid & 15;

    // GEMM1: cols cg*8 .. cg*8+7
    float acc[2][8];
#pragma unroll
    for (int j = 0; j < 2; j++)
#pragma unroll
        for (int i = 0; i < 8; i++) acc[j][i] = 0.0f;

    for (int k = 0; k < 64; ++k) {
        float2 xv = *(const float2*)&xs[k * 68 + SWZ(rg * 2, k)];
        float4 w0 = *(const float4*)&W2a[k * 128 + cg * 8];
        float4 w1 = *(const float4*)&W2a[k * 128 + cg * 8 + 4];
        float wv[8] = {w0.x, w0.y, w0.z, w0.w, w1.x, w1.y, w1.z, w1.w};
        float xr[2] = {xv.x, xv.y};
#pragma unroll
        for (int j = 0; j < 2; j++)
#pragma unroll
            for (int i = 0; i < 8; i++) acc[j][i] += xr[j] * wv[i];
    }

    // bias + relu + swizzled float2 store of H^T
#pragma unroll
    for (int i = 0; i < 8; i++) {
        float bi = b2a[cg * 8 + i];
        int c = cg * 8 + i;
        float2 hv = make_float2(fmaxf(acc[0][i] + bi, 0.0f),
                                fmaxf(acc[1][i] + bi, 0.0f));
        *(float2*)&hs[c * 68 + SWZ(rg * 2, c)] = hv;
    }
    __syncthreads();

    // GEMM2: cols cg*4 .. cg*4+3
    float a2[2][4];
#pragma unroll
    for (int j = 0; j < 2; j++)
#pragma unroll
        for (int i = 0; i < 4; i++) a2[j][i] = 0.0f;

    for (int k = 0; k < 128; ++k) {
        float2 hv = *(const float2*)&hs[k * 68 + SWZ(rg * 2, k)];
        float4 w = *(const float4*)&W2b[k * 64 + cg * 4];
        float wv[4] = {w.x, w.y, w.z, w.w};
        float hr[2] = {hv.x, hv.y};
#pragma unroll
        for (int j = 0; j < 2; j++)
#pragma unroll
            for (int i = 0; i < 4; i++) a2[j][i] += hr[j] * wv[i];
    }

#pragma unroll
    for (int i = 0; i < 4; i++) {
        float bi = b2b[cg * 4 + i];
#pragma unroll
        for (int j = 0; j < 2; j++) a2[j][i] += bi;
    }

    // l2norm per row: reduce squares across the 16 cg lanes (consecutive)
#pragma unroll
    for (int j = 0; j < 2; j++) {
        float ss = a2[j][0] * a2[j][0] + a2[j][1] * a2[j][1] +
                   a2[j][2] * a2[j][2] + a2[j][3] * a2[j][3];
#pragma unroll
        for (int m = 1; m < 16; m <<= 1) ss += __shfl_xor(ss, m, 64);
        float invn = 1.0f / fmaxf(sqrtf(ss), EPSV);
        int n = n0 + rg * 2 + j;
        if (n < N) {
            float4 o = make_float4(a2[j][0] * invn, a2[j][1] * invn,
                                   a2[j][2] * invn, a2[j][3] * invn);
            *(float4*)&out[(size_t)n * 64 + cg * 4] = o;
        }
    }
}

extern "C" void kernel_launch(void* const* d_in, const int* in_sizes, int n_in,
                              void* d_out, int out_size, void* d_ws, size_t ws_size,
                              hipStream_t stream) {
    const float* x   = (const float*)d_in[0];
    const float* K   = (const float*)d_in[1];
    const int*   ei  = (const int*)d_in[2];
    const float* W1  = (const float*)d_in[3];
    const float* b1  = (const float*)d_in[4];
    const float* W2a = (const float*)d_in[5];
    const float* b2a = (const float*)d_in[6];
    const float* W2b = (const float*)d_in[7];
    const float* b2b = (const float*)d_in[8];
    float* out = (float*)d_out;

    const int D  = 16;
    const int NK = 2;
    const int N  = in_sizes[0] / D;        // 50000
    const int E  = in_sizes[1] / NK;       // 1600000
    const int nbuck = (N + 511) >> 9;      // 98 <= NBMAX
    const int HROWS = 256;                 // bhist blocks

    // workspace layout:
    //   region0: staging int4 E*16 (overlaid after partB by h1[N*32]|h2[N*64])
    //   then: srcS[E] | kS[E] (float2) | off[N+1] | cntmat[HROWS*NBMAX] |
    //         bbase[NBMAX+1] | bcur[NBMAX*BCPAD] | flag[1]
    size_t region0 = (size_t)E * 16;
    size_t hbytes  = (size_t)N * 96 * 4;
    if (hbytes > region0) region0 = hbytes;

    float* h1     = (float*)d_ws;
    float* h2     = h1 + (size_t)N * 32;
    int4* staging = (int4*)d_ws;
    int* srcS     = (int*)((char*)d_ws + region0);
    float2* kS    = (float2*)(srcS + (size_t)E);
    int* off      = (int*)(kS + (size_t)E);
    int* cntmat   = off + (N + 1);
    int* bbase    = cntmat + HROWS * NBMAX;
    int* bcur     = bbase + NBMAX + 1;
    int* flag     = bcur + NBMAX * BCPAD;

    detect_i64_kernel<<<1, 64, 0, stream>>>(ei, flag);
    bhist_kernel<<<HROWS, 256, 0, stream>>>(ei, flag, cntmat, E);
    bscan_kernel<<<1, NBMAX, 0, stream>>>(cntmat, bbase, bcur, off,
                                          nbuck, E, HROWS, N);

    int ablocks = (E + CHUNK - 1) / CHUNK;
    partA_kernel<<<ablocks, 256, 0, stream>>>(K, ei, flag, bcur, staging, E);
    partB_kernel<<<nbuck, 1024, 0, stream>>>(staging, bbase, off, srcS, kS, N);

    conv1_mlp1_kernel<<<(N + 7) / 8, 256, 0, stream>>>(x, srcS, kS, off,
                                                       W1, b1, h1, N);
    conv2_gather_kernel<<<(N + 3) / 4, 256, 0, stream>>>(h1, srcS, kS, off,
                                                         h2, N);
    mlp2_kernel<<<(N + 63) / 64, 512, 0, stream>>>(h2, W2a, b2a, W2b, b2b,
                                                   out, N);
}

// Round 10
// 245.311 us; speedup vs baseline: 1.0016x; 1.0016x over previous
//
#include <hip/hip_runtime.h>
#include <hip/hip_bf16.h>

// Pipeline (N=50000, E=1.6M, D=16, NK=2):
//   bhist: LDS-private bucket histogram (bucket = dst>>9)
//   bscan: column-sum + scan buckets -> bbase/bcur(padded)/off[N]=E sentinel
//   partA: bucket-partition edges into staging (LDS-staged, coalesced writes)
//   partB: per-bucket node sort -> srcS/kS dst-sorted + off (L2-local writes)
//   conv1+mlp1: half-wave/node, 16-lane group per edge, dual k-acc
//   conv2:      wave per node, 8-lane group per edge, float4 row gather
//   mlp2:       128-thread, 64 nodes, acc[8][8] fat-tile GEMM (0.5B W/FLOP)
//
// NOTE (round-7): NEVER atomicAdd on __shared__ float in hot loops (678us).
// NOTE (round-8/9): mlp2 time tracks W-bytes-per-FLOP, NOT bank conflicts.
//   acc[4][8] (1B/FLOP) = 45us; acc[2][8] (2B/FLOP) = 68us despite fewer
//   conflicts. This version: acc[8][8] = 0.5B/FLOP.

#define EPSV 1e-12f
#define CHUNK 2048      // edges per partA block
#define NBMAX 128       // bucket slots (nbuck = ceil(N/512) = 98 <= 128)
#define BNODES 512      // nodes per partition bucket (dst >> 9)
#define BCPAD 16        // bcur padding stride (ints) -> 1 cache line per bucket

// ---- detect whether edge_index buffer is int64 (odd int32 words all zero) ----
__global__ void detect_i64_kernel(const int* ei, int* flag) {
    int lane = threadIdx.x;
    int nonzero = 0;
    for (int i = lane; i < 1024; i += 64) {
        if (ei[2 * i + 1] != 0) nonzero = 1;
    }
    unsigned long long b = __ballot(nonzero);
    if (lane == 0) *flag = (b == 0ull) ? 1 : 0;   // 1 => int64 layout
}

__device__ __forceinline__ void load_edge(const int* ei, int e, int E, int flag,
                                          int& src, int& dst) {
    if (flag) {            // int64 storage: low words at even int32 indices
        src = ei[2 * e];
        dst = ei[2 * E + 2 * e];
    } else {               // int32 storage
        src = ei[e];
        dst = ei[E + e];
    }
}

// ---- bucket histogram: LDS-privatized, one cntmat row per block ----
__global__ __launch_bounds__(256) void bhist_kernel(
        const int* __restrict__ ei, const int* __restrict__ flagp,
        int* __restrict__ cntmat, int E) {
    __shared__ int l[NBMAX];
    if (threadIdx.x < NBMAX) l[threadIdx.x] = 0;
    __syncthreads();
    int flag = *flagp;
    int stride = gridDim.x * 256;
    for (int e = blockIdx.x * 256 + threadIdx.x; e < E; e += stride) {
        int dst = flag ? ei[2 * E + 2 * e] : ei[E + e];
        atomicAdd(&l[dst >> 9], 1);
    }
    __syncthreads();
    if (threadIdx.x < NBMAX) cntmat[blockIdx.x * NBMAX + threadIdx.x] = l[threadIdx.x];
}

// ---- column-sum cntmat + exclusive scan of bucket counts ----
__global__ void bscan_kernel(const int* __restrict__ cntmat,
                             int* __restrict__ bbase, int* __restrict__ bcur,
                             int* __restrict__ off,
                             int nbuck, int E, int nrows, int N) {
    __shared__ int s[NBMAX];
    int t = threadIdx.x;            // blockDim = NBMAX
    int c = 0;
    for (int i = 0; i < nrows; ++i) c += cntmat[i * NBMAX + t];
    s[t] = c;
    __syncthreads();
    for (int d = 1; d < NBMAX; d <<= 1) {
        int v = (t >= d) ? s[t - d] : 0;
        __syncthreads();
        s[t] += v;
        __syncthreads();
    }
    int excl = s[t] - c;
    if (t < nbuck) { bbase[t] = excl; bcur[t * BCPAD] = excl; }
    if (t == 0) { bbase[nbuck] = E; off[N] = E; }
}

// ---- partA: bucket-partition edges by dst>>9, LDS-staged ----
__global__ __launch_bounds__(256) void partA_kernel(
        const float* __restrict__ K, const int* __restrict__ ei,
        const int* __restrict__ flagp, int* __restrict__ bcur,
        int4* __restrict__ staging, int E) {
    __shared__ int cnt[NBMAX];
    __shared__ int bexc[NBMAX];
    __shared__ int gbase[NBMAX];
    __shared__ int scanbuf[NBMAX];
    __shared__ int4 stage[CHUNK];     // 32 KB

    int flag = *flagp;
    int e0 = blockIdx.x * CHUNK;
    int tot = min(CHUNK, E - e0);

    for (int b = threadIdx.x; b < NBMAX; b += 256) cnt[b] = 0;
    __syncthreads();

    int  myslot[CHUNK / 256];
    int  mybk[CHUNK / 256];
    int4 myrec[CHUNK / 256];
#pragma unroll
    for (int it = 0; it < CHUNK / 256; ++it) {
        int e = e0 + it * 256 + threadIdx.x;
        mybk[it] = -1;
        if (e < E) {
            int src, dst;
            load_edge(ei, e, E, flag, src, dst);
            int bk = dst >> 9;
            mybk[it] = bk;
            myrec[it] = make_int4(src, __float_as_int(K[e]),
                                  __float_as_int(K[E + e]), dst);
            myslot[it] = atomicAdd(&cnt[bk], 1);
        }
    }
    __syncthreads();

    if (threadIdx.x < NBMAX) scanbuf[threadIdx.x] = cnt[threadIdx.x];
    __syncthreads();
    for (int d = 1; d < NBMAX; d <<= 1) {
        int v = 0;
        if (threadIdx.x < NBMAX && threadIdx.x >= d) v = scanbuf[threadIdx.x - d];
        __syncthreads();
        if (threadIdx.x < NBMAX) scanbuf[threadIdx.x] += v;
        __syncthreads();
    }
    if (threadIdx.x < NBMAX) {
        int c = cnt[threadIdx.x];
        bexc[threadIdx.x] = scanbuf[threadIdx.x] - c;
        gbase[threadIdx.x] = c ? atomicAdd(&bcur[threadIdx.x * BCPAD], c) : 0;
    }
    __syncthreads();

#pragma unroll
    for (int it = 0; it < CHUNK / 256; ++it) {
        if (mybk[it] >= 0) stage[bexc[mybk[it]] + myslot[it]] = myrec[it];
    }
    __syncthreads();

    for (int i = threadIdx.x; i < tot; i += 256) {
        int4 r = stage[i];
        int bk = r.w >> 9;
        staging[gbase[bk] + (i - bexc[bk])] = r;
    }
}

// ---- partB: per-bucket node sort; emits dst-sorted srcS/kS + off ----
__global__ __launch_bounds__(1024) void partB_kernel(
        const int4* __restrict__ staging, const int* __restrict__ bbase,
        int* __restrict__ off, int* __restrict__ srcS,
        float2* __restrict__ kS, int N) {
    __shared__ int lcnt[BNODES];
    __shared__ int lscan[BNODES];

    int b = blockIdx.x;
    int nodeBase = b << 9;
    int s0 = bbase[b];
    int s1 = bbase[b + 1];
    int t = threadIdx.x;

    if (t < BNODES) lcnt[t] = 0;
    __syncthreads();

    for (int i = s0 + t; i < s1; i += 1024)
        atomicAdd(&lcnt[staging[i].w - nodeBase], 1);
    __syncthreads();

    if (t < BNODES) lscan[t] = lcnt[t];
    __syncthreads();
    for (int d = 1; d < BNODES; d <<= 1) {
        int v = 0;
        if (t < BNODES && t >= d) v = lscan[t - d];
        __syncthreads();
        if (t < BNODES) lscan[t] += v;
        __syncthreads();
    }
    if (t < BNODES) {
        int node = nodeBase + t;
        if (node < N) {
            int c = lcnt[t];
            int o = s0 + lscan[t] - c;   // exclusive offset, absolute
            off[node] = o;
            lcnt[t] = o;                 // becomes the cursor
        }
    }
    __syncthreads();

    for (int i = s0 + t; i < s1; i += 1024) {
        int4 r = staging[i];
        int pos = atomicAdd(&lcnt[r.w - nodeBase], 1);
        srcS[pos] = r.x;
        kS[pos] = make_float2(__int_as_float(r.y), __int_as_float(r.z));
    }
}

// ---- conv1 + MLP1: half-wave per node; 16-lane group per edge ----
__global__ __launch_bounds__(256) void conv1_mlp1_kernel(
        const float* __restrict__ x, const int* __restrict__ srcS,
        const float2* __restrict__ kS, const int* __restrict__ off,
        const float* __restrict__ W1, const float* __restrict__ b1,
        float* __restrict__ h1, int N) {
    __shared__ float w[1024];
    __shared__ float bsh[32];
    for (int i = threadIdx.x; i < 1024; i += 256) w[i] = W1[i];
    if (threadIdx.x < 32) bsh[threadIdx.x] = b1[threadIdx.x];
    __syncthreads();

    int hw = threadIdx.x >> 5;        // half-wave 0..7 -> node
    int lane = threadIdx.x & 31;
    int node = blockIdx.x * 8 + hw;
    if (node >= N) return;

    int ch = lane & 15;
    int grp = lane >> 4;              // 0/1: edge parity
    int start = off[node];
    int deg = off[node + 1] - start;

    float a0 = 0.f, a1 = 0.f;
    int j = grp;
    for (; j + 6 < deg; j += 8) {     // edges j, j+2, j+4, j+6
        int p = start + j;
        int s0 = srcS[p], s1 = srcS[p + 2], s2 = srcS[p + 4], s3 = srcS[p + 6];
        float2 k0 = kS[p], k1 = kS[p + 2], k2 = kS[p + 4], k3 = kS[p + 6];
        float v0 = x[s0 * 16 + ch];
        float v1 = x[s1 * 16 + ch];
        float v2 = x[s2 * 16 + ch];
        float v3 = x[s3 * 16 + ch];
        a0 += k0.x * v0; a1 += k0.y * v0;
        a0 += k1.x * v1; a1 += k1.y * v1;
        a0 += k2.x * v2; a1 += k2.y * v2;
        a0 += k3.x * v3; a1 += k3.y * v3;
    }
    for (; j < deg; j += 2) {
        int p = start + j;
        int s = srcS[p];
        float2 kk = kS[p];
        float v = x[s * 16 + ch];
        a0 += kk.x * v; a1 += kk.y * v;
    }
    a0 += __shfl_xor(a0, 16, 32);
    a1 += __shfl_xor(a1, 16, 32);
    float acc = grp ? a1 : a0;

    float o = bsh[lane];
#pragma unroll
    for (int q = 0; q < 32; q++) o += __shfl(acc, q, 32) * w[q * 32 + lane];
    o = fmaxf(o, 0.f);
    float ss = o * o;
#pragma unroll
    for (int m = 16; m >= 1; m >>= 1) ss += __shfl_xor(ss, m, 32);
    h1[node * 32 + lane] = o / fmaxf(sqrtf(ss), EPSV);
}

// ---- conv2: wave per node; 8-lane group per edge; float4 row gather ----
__global__ __launch_bounds__(256) void conv2_gather_kernel(
        const float* __restrict__ h1, const int* __restrict__ srcS,
        const float2* __restrict__ kS, const int* __restrict__ off,
        float* __restrict__ h2, int N) {
    int wid = threadIdx.x >> 6;
    int lane = threadIdx.x & 63;
    int node = blockIdx.x * 4 + wid;
    if (node >= N) return;

    int grp = lane >> 3;              // 0..7: edge index mod 8
    int cq = lane & 7;                // channel quad: ch = cq*4..cq*4+3
    int start = off[node];
    int deg = off[node + 1] - start;

    float a00 = 0.f, a01 = 0.f, a02 = 0.f, a03 = 0.f;   // k0 * row[cq*4..]
    float a10 = 0.f, a11 = 0.f, a12 = 0.f, a13 = 0.f;   // k1 * row[cq*4..]
    int j = grp;
    for (; j + 8 < deg; j += 16) {    // edges j, j+8
        int p0 = start + j, p1 = start + j + 8;
        int s0 = srcS[p0], s1 = srcS[p1];
        float2 k0 = kS[p0], k1 = kS[p1];
        float4 v0 = *(const float4*)&h1[s0 * 32 + cq * 4];
        float4 v1 = *(const float4*)&h1[s1 * 32 + cq * 4];
        a00 += k0.x * v0.x; a01 += k0.x * v0.y; a02 += k0.x * v0.z; a03 += k0.x * v0.w;
        a10 += k0.y * v0.x; a11 += k0.y * v0.y; a12 += k0.y * v0.z; a13 += k0.y * v0.w;
        a00 += k1.x * v1.x; a01 += k1.x * v1.y; a02 += k1.x * v1.z; a03 += k1.x * v1.w;
        a10 += k1.y * v1.x; a11 += k1.y * v1.y; a12 += k1.y * v1.z; a13 += k1.y * v1.w;
    }
    for (; j < deg; j += 8) {
        int p = start + j;
        int s = srcS[p];
        float2 kk = kS[p];
        float4 v = *(const float4*)&h1[s * 32 + cq * 4];
        a00 += kk.x * v.x; a01 += kk.x * v.y; a02 += kk.x * v.z; a03 += kk.x * v.w;
        a10 += kk.y * v.x; a11 += kk.y * v.y; a12 += kk.y * v.z; a13 += kk.y * v.w;
    }

#pragma unroll
    for (int m = 8; m < 64; m <<= 1) {
        a00 += __shfl_xor(a00, m, 64); a01 += __shfl_xor(a01, m, 64);
        a02 += __shfl_xor(a02, m, 64); a03 += __shfl_xor(a03, m, 64);
        a10 += __shfl_xor(a10, m, 64); a11 += __shfl_xor(a11, m, 64);
        a12 += __shfl_xor(a12, m, 64); a13 += __shfl_xor(a13, m, 64);
    }
    if (grp == 0) {
        float4 o = make_float4(a00, a01, a02, a03);
        *(float4*)&h2[(size_t)node * 64 + cq * 4] = o;
    } else if (grp == 1) {
        float4 o = make_float4(a10, a11, a12, a13);
        *(float4*)&h2[(size_t)node * 64 + 32 + cq * 4] = o;
    }
}

// ---- MLP2: 128 threads, 64 nodes/block, acc[8][8] fat tiles ----
// k-major LDS tiles, store/read col swizzle: col' = (n + 4*(c>>3)) & 63.
// Reads: 4 distinct banks x 16-lane broadcast = conflict-free.
#define SWZ(n, c) (((n) + (((c) >> 3) << 2)) & 63)
__global__ __launch_bounds__(128) void mlp2_kernel(
        const float* __restrict__ h2,
        const float* __restrict__ W2a,
        const float* __restrict__ b2a,
        const float* __restrict__ W2b,
        const float* __restrict__ b2b,
        float* __restrict__ out, int N) {
    __shared__ float xs[64 * 68];    // xs[k][n'] k in [0,64)
    __shared__ float hs[128 * 68];   // hs[c][n'] c in [0,128)

    int tid = threadIdx.x;
    int n0 = blockIdx.x * 64;

    // load + transpose-swizzle X = h2[n0..n0+63][0..63]
#pragma unroll
    for (int it = 0; it < 8; ++it) {
        int idx = tid + it * 128;        // 0..1023
        int n = idx >> 4;
        int c4 = (idx & 15) * 4;
        float4 v = make_float4(0.f, 0.f, 0.f, 0.f);
        if (n0 + n < N) v = *(const float4*)&h2[(size_t)(n0 + n) * 64 + c4];
        float vv[4] = {v.x, v.y, v.z, v.w};
#pragma unroll
        for (int u = 0; u < 4; ++u) {
            int c = c4 + u;
            xs[c * 68 + SWZ(n, c)] = vv[u];
        }
    }
    __syncthreads();

    int rg = tid >> 4;     // 0..7: nodes rg*8 .. rg*8+7
    int cg = tid & 15;
    int nb = rg * 8;

    // GEMM1: H[nb..nb+7][cg*8..cg*8+7]
    float acc[8][8];
#pragma unroll
    for (int j = 0; j < 8; j++)
#pragma unroll
        for (int i = 0; i < 8; i++) acc[j][i] = 0.0f;

    for (int k = 0; k < 64; ++k) {
        float4 x0 = *(const float4*)&xs[k * 68 + SWZ(nb, k)];
        float4 x1 = *(const float4*)&xs[k * 68 + SWZ(nb + 4, k)];
        float4 w0 = *(const float4*)&W2a[k * 128 + cg * 8];
        float4 w1 = *(const float4*)&W2a[k * 128 + cg * 8 + 4];
        float xr[8] = {x0.x, x0.y, x0.z, x0.w, x1.x, x1.y, x1.z, x1.w};
        float wv[8] = {w0.x, w0.y, w0.z, w0.w, w1.x, w1.y, w1.z, w1.w};
#pragma unroll
        for (int j = 0; j < 8; j++)
#pragma unroll
            for (int i = 0; i < 8; i++) acc[j][i] += xr[j] * wv[i];
    }

    // bias + relu + swizzled float4 stores of H^T
#pragma unroll
    for (int i = 0; i < 8; i++) {
        int c = cg * 8 + i;
        float bi = b2a[c];
        float4 h0 = make_float4(fmaxf(acc[0][i] + bi, 0.f),
                                fmaxf(acc[1][i] + bi, 0.f),
                                fmaxf(acc[2][i] + bi, 0.f),
                                fmaxf(acc[3][i] + bi, 0.f));
        float4 h1v = make_float4(fmaxf(acc[4][i] + bi, 0.f),
                                 fmaxf(acc[5][i] + bi, 0.f),
                                 fmaxf(acc[6][i] + bi, 0.f),
                                 fmaxf(acc[7][i] + bi, 0.f));
        *(float4*)&hs[c * 68 + SWZ(nb, c)] = h0;
        *(float4*)&hs[c * 68 + SWZ(nb + 4, c)] = h1v;
    }
    __syncthreads();

    // GEMM2: O[nb..nb+7][cg*4..cg*4+3]
    float a2[8][4];
#pragma unroll
    for (int j = 0; j < 8; j++)
#pragma unroll
        for (int i = 0; i < 4; i++) a2[j][i] = 0.0f;

    for (int k = 0; k < 128; ++k) {
        float4 h0 = *(const float4*)&hs[k * 68 + SWZ(nb, k)];
        float4 h1v = *(const float4*)&hs[k * 68 + SWZ(nb + 4, k)];
        float4 w = *(const float4*)&W2b[k * 64 + cg * 4];
        float hr[8] = {h0.x, h0.y, h0.z, h0.w, h1v.x, h1v.y, h1v.z, h1v.w};
        float wv[4] = {w.x, w.y, w.z, w.w};
#pragma unroll
        for (int j = 0; j < 8; j++)
#pragma unroll
            for (int i = 0; i < 4; i++) a2[j][i] += hr[j] * wv[i];
    }

#pragma unroll
    for (int i = 0; i < 4; i++) {
        float bi = b2b[cg * 4 + i];
#pragma unroll
        for (int j = 0; j < 8; j++) a2[j][i] += bi;
    }

    // l2norm per node row: reduce squares across the 16 cg lanes
#pragma unroll
    for (int j = 0; j < 8; j++) {
        float ss = a2[j][0] * a2[j][0] + a2[j][1] * a2[j][1] +
                   a2[j][2] * a2[j][2] + a2[j][3] * a2[j][3];
#pragma unroll
        for (int m = 1; m < 16; m <<= 1) ss += __shfl_xor(ss, m, 64);
        float invn = 1.0f / fmaxf(sqrtf(ss), EPSV);
        int n = n0 + nb + j;
        if (n < N) {
            float4 o = make_float4(a2[j][0] * invn, a2[j][1] * invn,
                                   a2[j][2] * invn, a2[j][3] * invn);
            *(float4*)&out[(size_t)n * 64 + cg * 4] = o;
        }
    }
}

extern "C" void kernel_launch(void* const* d_in, const int* in_sizes, int n_in,
                              void* d_out, int out_size, void* d_ws, size_t ws_size,
                              hipStream_t stream) {
    const float* x   = (const float*)d_in[0];
    const float* K   = (const float*)d_in[1];
    const int*   ei  = (const int*)d_in[2];
    const float* W1  = (const float*)d_in[3];
    const float* b1  = (const float*)d_in[4];
    const float* W2a = (const float*)d_in[5];
    const float* b2a = (const float*)d_in[6];
    const float* W2b = (const float*)d_in[7];
    const float* b2b = (const float*)d_in[8];
    float* out = (float*)d_out;

    const int D  = 16;
    const int NK = 2;
    const int N  = in_sizes[0] / D;        // 50000
    const int E  = in_sizes[1] / NK;       // 1600000
    const int nbuck = (N + 511) >> 9;      // 98 <= NBMAX
    const int HROWS = 256;                 // bhist blocks

    // workspace layout:
    //   region0: staging int4 E*16 (overlaid after partB by h1[N*32]|h2[N*64])
    //   then: srcS[E] | kS[E] (float2) | off[N+1] | cntmat[HROWS*NBMAX] |
    //         bbase[NBMAX+1] | bcur[NBMAX*BCPAD] | flag[1]
    size_t region0 = (size_t)E * 16;
    size_t hbytes  = (size_t)N * 96 * 4;
    if (hbytes > region0) region0 = hbytes;

    float* h1     = (float*)d_ws;
    float* h2     = h1 + (size_t)N * 32;
    int4* staging = (int4*)d_ws;
    int* srcS     = (int*)((char*)d_ws + region0);
    float2* kS    = (float2*)(srcS + (size_t)E);
    int* off      = (int*)(kS + (size_t)E);
    int* cntmat   = off + (N + 1);
    int* bbase    = cntmat + HROWS * NBMAX;
    int* bcur     = bbase + NBMAX + 1;
    int* flag     = bcur + NBMAX * BCPAD;

    detect_i64_kernel<<<1, 64, 0, stream>>>(ei, flag);
    bhist_kernel<<<HROWS, 256, 0, stream>>>(ei, flag, cntmat, E);
    bscan_kernel<<<1, NBMAX, 0, stream>>>(cntmat, bbase, bcur, off,
                                          nbuck, E, HROWS, N);

    int ablocks = (E + CHUNK - 1) / CHUNK;
    partA_kernel<<<ablocks, 256, 0, stream>>>(K, ei, flag, bcur, staging, E);
    partB_kernel<<<nbuck, 1024, 0, stream>>>(staging, bbase, off, srcS, kS, N);

    conv1_mlp1_kernel<<<(N + 7) / 8, 256, 0, stream>>>(x, srcS, kS, off,
                                                       W1, b1, h1, N);
    conv2_gather_kernel<<<(N + 3) / 4, 256, 0, stream>>>(h1, srcS, kS, off,
                                                         h2, N);
    mlp2_kernel<<<(N + 63) / 64, 128, 0, stream>>>(h2, W2a, b2a, W2b, b2b,
                                                   out, N);
}